// Round 8
// baseline (489.335 us; speedup 1.0000x reference)
//
#include <hip/hip_runtime.h>
#include <cstdint>

#define RELU_COEF 0.05f
#define LEAKY(v) ((v) > 0.f ? (v) : RELU_COEF * (v))

typedef __attribute__((ext_vector_type(8))) short short8;
typedef __attribute__((ext_vector_type(4))) float f32x4;

#define MFMA(acc, a, b) \
    acc = __builtin_amdgcn_mfma_f32_16x16x32_bf16(a, b, acc, 0, 0, 0)

__device__ inline ushort f2bf(float f) {
    union { float f; uint32_t u; } v; v.f = f;
    return (ushort)((v.u + 0x7FFFu + ((v.u >> 16) & 1u)) >> 16);
}
__device__ inline float bf2f(ushort h) {
    union { uint32_t u; float f; } v; v.u = ((uint32_t)h) << 16;
    return v.f;
}
__device__ inline float u2f(uint32_t u) {
    union { uint32_t u; float f; } v; v.u = u; return v.f;
}
__device__ inline void split8(const float* p, short8& h8, short8& l8) {
    float4 a = *(const float4*)p;
    float4 b = *(const float4*)(p + 4);
    float v[8] = {a.x, a.y, a.z, a.w, b.x, b.y, b.z, b.w};
    short8 hh, ll;
#pragma unroll
    for (int i = 0; i < 8; ++i) {
        ushort hi = f2bf(v[i]);
        hh[i] = (short)hi;
        ll[i] = (short)f2bf(v[i] - bf2f(hi));
    }
    h8 = hh; l8 = ll;
}

// ---------------------------------------------------------------------------
// CSR build
// ---------------------------------------------------------------------------
__global__ __launch_bounds__(256) void hist_kernel(
    const int* __restrict__ ei, int* __restrict__ deg, int E)
{
    int e = blockIdx.x * 256 + threadIdx.x;
    if (e >= E) return;
    atomicAdd(&deg[ei[(size_t)E + e]], 1);
}

__global__ __launch_bounds__(256) void scan1_kernel(
    const int* __restrict__ in, int* __restrict__ out, int* __restrict__ bsum, int N)
{
    __shared__ int ts[256];
    int tid = threadIdx.x;
    int base = blockIdx.x * 1024 + tid * 4;
    int v[4];
    int s = 0;
#pragma unroll
    for (int j = 0; j < 4; ++j) {
        int idx = base + j;
        v[j] = (idx < N) ? in[idx] : 0;
        s += v[j];
    }
    ts[tid] = s;
    __syncthreads();
    for (int off = 1; off < 256; off <<= 1) {
        int t = (tid >= off) ? ts[tid - off] : 0;
        __syncthreads();
        ts[tid] += t;
        __syncthreads();
    }
    int excl = ts[tid] - s;
    if (tid == 255) bsum[blockIdx.x] = ts[255];
    int run = excl;
#pragma unroll
    for (int j = 0; j < 4; ++j) {
        int idx = base + j;
        if (idx < N) out[idx] = run;
        run += v[j];
    }
}

__global__ __launch_bounds__(512) void scan2_kernel(int* bsum, int nb)
{
    __shared__ int ts[512];
    int tid = threadIdx.x;
    int v = (tid < nb) ? bsum[tid] : 0;
    ts[tid] = v;
    __syncthreads();
    for (int off = 1; off < 512; off <<= 1) {
        int t = (tid >= off) ? ts[tid - off] : 0;
        __syncthreads();
        ts[tid] += t;
        __syncthreads();
    }
    if (tid < nb) bsum[tid] = ts[tid] - v;
}

__global__ __launch_bounds__(256) void scan3_kernel(
    int* __restrict__ rowptr, const int* __restrict__ bsum, int N, int E)
{
    int idx = blockIdx.x * 256 + threadIdx.x;
    if (idx < N) rowptr[idx] += bsum[idx >> 10];
    if (idx == 0) rowptr[N] = E;
}

__global__ __launch_bounds__(256) void fill_kernel(
    const int* __restrict__ ei, const float* __restrict__ ea,
    int* __restrict__ cursor, int* __restrict__ csrc, float* __restrict__ cw, int E)
{
    int e = blockIdx.x * 256 + threadIdx.x;
    if (e >= E) return;
    int t = ei[(size_t)E + e];
    int pos = atomicAdd(&cursor[t], 1);
    csrc[pos] = ei[e];
    cw[pos] = ea[e];
}

// ---------------------------------------------------------------------------
// x -> bf16 copy (gather payload for conv1)
// ---------------------------------------------------------------------------
__global__ __launch_bounds__(256) void xbf_kernel(
    const float* __restrict__ x, ushort* __restrict__ xbf, int total4)
{
    int i = blockIdx.x * 256 + threadIdx.x;
    if (i >= total4) return;
    float4 v = *(const float4*)(x + (size_t)i * 4);
    ushort4 h;
    h.x = f2bf(v.x); h.y = f2bf(v.y); h.z = f2bf(v.z); h.w = f2bf(v.w);
    *(ushort4*)(xbf + (size_t)i * 4) = h;
}

// ---------------------------------------------------------------------------
// Weight prep -> fragment-major split-bf16 layouts (coalesced B loads):
// W1f[kk:4][hl:2][kc:4][n:128][e:8]   (K=128: agg1|x)
// W2f[kk:8][hl:2][kc:4][n:128][e:8]   (K=256: agg2|h1)
// Wgf[kk:6][p:4 (sH,sL,tH,tL)][kc:4][n:128][e:8]  (K=192: h2|x)
// ---------------------------------------------------------------------------
__global__ __launch_bounds__(256) void prep_weights_kernel(
    const float* __restrict__ Wrel1, const float* __restrict__ Wroot1,
    const float* __restrict__ Wrel2, const float* __restrict__ Wroot2,
    const float* __restrict__ Wsig, const float* __restrict__ Wtanh,
    ushort* __restrict__ W1f, ushort* __restrict__ W2f, ushort* __restrict__ Wgf)
{
    int gid = blockIdx.x * 256 + threadIdx.x;
    if (gid < 32768) {
        int e = gid & 7, nn = (gid >> 3) & 127, kc = (gid >> 10) & 3;
        int hl = (gid >> 12) & 1, kk = gid >> 13;
        int k = kk * 32 + kc * 8 + e;
        float v = (k < 64) ? Wrel1[(size_t)k * 128 + nn]
                           : Wroot1[(size_t)(k - 64) * 128 + nn];
        ushort hi = f2bf(v);
        W1f[gid] = hl ? f2bf(v - bf2f(hi)) : hi;
        return;
    }
    int g2 = gid - 32768;
    if (g2 < 65536) {
        int e = g2 & 7, nn = (g2 >> 3) & 127, kc = (g2 >> 10) & 3;
        int hl = (g2 >> 12) & 1, kk = g2 >> 13;
        int k = kk * 32 + kc * 8 + e;
        float v = (k < 128) ? Wrel2[(size_t)k * 128 + nn]
                            : Wroot2[(size_t)(k - 128) * 128 + nn];
        ushort hi = f2bf(v);
        W2f[g2] = hl ? f2bf(v - bf2f(hi)) : hi;
        return;
    }
    int g3 = g2 - 65536;
    if (g3 < 98304) {
        int e = g3 & 7, nn = (g3 >> 3) & 127, kc = (g3 >> 10) & 3;
        int p = (g3 >> 12) & 3, kk = g3 >> 14;
        int k = kk * 32 + kc * 8 + e;
        float v = (p < 2) ? Wsig[(size_t)k * 128 + nn]
                          : Wtanh[(size_t)k * 128 + nn];
        ushort hi = f2bf(v);
        Wgf[g3] = (p & 1) ? f2bf(v - bf2f(hi)) : hi;
    }
}

// ---------------------------------------------------------------------------
// Fused conv1 (32-row tile): paired-edge gather (2 edges/slot, 8B/lane),
// then h1bf = bf16(leaky([agg1|x]@W1 + b))
// ---------------------------------------------------------------------------
__global__ __launch_bounds__(256) void conv1_fused_kernel(
    const float* __restrict__ x, const ushort* __restrict__ xbf,
    const int* __restrict__ rowptr,
    const int* __restrict__ csrc, const float* __restrict__ cw,
    const ushort* __restrict__ W1f, const float* __restrict__ brel,
    ushort* __restrict__ h1bf, int n)
{
    __shared__ __align__(16) float agg[32 * 68];   // 8704 B

    int tid = threadIdx.x;
    int lane = tid & 63;
    int wv = tid >> 6;
    int mr = lane & 15;
    int kc = lane >> 4;          // 0..3
    int i0 = blockIdx.x * 32;

    // ---- gather: 32 lanes/node (2 edges x 16 lanes x 8B), 8 nodes, 4 iters ----
    {
        int q = tid & 31;
        int g = tid >> 5;
        int sub = q >> 4;        // 0: even edge of pair, 1: odd edge
        int ql = q & 15;         // 8B chunk (4 dims)
#pragma unroll
        for (int it = 0; it < 4; ++it) {
            int rl = it * 8 + g;
            int node = i0 + rl;
            float a0 = 0.f, a1 = 0.f, a2 = 0.f, a3 = 0.f;
            if (node < n) {
                int b = rowptr[node], e = rowptr[node + 1];
                for (int cb = b; cb < e; cb += 32) {
                    int cnt = e - cb; if (cnt > 32) cnt = 32;
                    int sIdx = 0; float sW = 0.f;
                    if (q < cnt) { sIdx = csrc[cb + q]; sW = cw[cb + q]; }
                    int pairs = (cnt + 1) >> 1;
                    int p = 0;
                    for (; p + 8 <= pairs; p += 8) {      // 16 edges in flight
                        int si[8]; float wj[8]; uint2 v[8];
#pragma unroll
                        for (int u = 0; u < 8; ++u) {
                            int j = 2 * (p + u) + sub;
                            int jc = j < cnt ? j : cnt - 1;
                            si[u] = __shfl(sIdx, jc, 32);
                            float t = __shfl(sW, jc, 32);
                            wj[u] = (j < cnt) ? t : 0.f;
                        }
#pragma unroll
                        for (int u = 0; u < 8; ++u)
                            v[u] = *(const uint2*)(xbf + (size_t)si[u] * 64 + ql * 4);
#pragma unroll
                        for (int u = 0; u < 8; ++u) {
                            a0 += wj[u] * u2f(v[u].x << 16);
                            a1 += wj[u] * u2f(v[u].x & 0xFFFF0000u);
                            a2 += wj[u] * u2f(v[u].y << 16);
                            a3 += wj[u] * u2f(v[u].y & 0xFFFF0000u);
                        }
                    }
                    for (; p < pairs; ++p) {
                        int j = 2 * p + sub;
                        int jc = j < cnt ? j : cnt - 1;
                        int s0 = __shfl(sIdx, jc, 32);
                        float t = __shfl(sW, jc, 32);
                        float w0 = (j < cnt) ? t : 0.f;
                        uint2 v0 = *(const uint2*)(xbf + (size_t)s0 * 64 + ql * 4);
                        a0 += w0 * u2f(v0.x << 16);
                        a1 += w0 * u2f(v0.x & 0xFFFF0000u);
                        a2 += w0 * u2f(v0.y << 16);
                        a3 += w0 * u2f(v0.y & 0xFFFF0000u);
                    }
                }
            }
            // merge even/odd partial sums
            a0 += __shfl_xor(a0, 16, 32);
            a1 += __shfl_xor(a1, 16, 32);
            a2 += __shfl_xor(a2, 16, 32);
            a3 += __shfl_xor(a3, 16, 32);
            if (sub == 0)
                *(float2*)&agg[rl * 68 + ql * 4]     = make_float2(a0, a1);
            else
                *(float2*)&agg[rl * 68 + ql * 4 + 2] = make_float2(a2, a3);
        }
    }
    __syncthreads();

    // ---- GEMM ----
    int t0 = wv * 2;
    const ushort* Wp = W1f + kc * 1024 + t0 * 128 + mr * 8;
    f32x4 acc[2][2] = {};

#pragma unroll
    for (int kk = 0; kk < 2; ++kk) {      // A from LDS agg (K 0..63)
        short8 bH0 = *(const short8*)(Wp + kk * 8192);
        short8 bH1 = *(const short8*)(Wp + kk * 8192 + 128);
        short8 bL0 = *(const short8*)(Wp + kk * 8192 + 4096);
        short8 bL1 = *(const short8*)(Wp + kk * 8192 + 4096 + 128);
#pragma unroll
        for (int sub = 0; sub < 2; ++sub) {
            short8 aH, aL;
            split8(&agg[(sub * 16 + mr) * 68 + kk * 32 + kc * 8], aH, aL);
            MFMA(acc[sub][0], aH, bH0); MFMA(acc[sub][0], aH, bL0); MFMA(acc[sub][0], aL, bH0);
            MFMA(acc[sub][1], aH, bH1); MFMA(acc[sub][1], aH, bL1); MFMA(acc[sub][1], aL, bH1);
        }
    }
#pragma unroll
    for (int kk = 2; kk < 4; ++kk) {      // A from x (K 64..127), exact split
        short8 bH0 = *(const short8*)(Wp + kk * 8192);
        short8 bH1 = *(const short8*)(Wp + kk * 8192 + 128);
        short8 bL0 = *(const short8*)(Wp + kk * 8192 + 4096);
        short8 bL1 = *(const short8*)(Wp + kk * 8192 + 4096 + 128);
#pragma unroll
        for (int sub = 0; sub < 2; ++sub) {
            int row = i0 + sub * 16 + mr; if (row > n - 1) row = n - 1;
            short8 aH, aL;
            split8(x + (size_t)row * 64 + (kk - 2) * 32 + kc * 8, aH, aL);
            MFMA(acc[sub][0], aH, bH0); MFMA(acc[sub][0], aH, bL0); MFMA(acc[sub][0], aL, bH0);
            MFMA(acc[sub][1], aH, bH1); MFMA(acc[sub][1], aH, bL1); MFMA(acc[sub][1], aL, bH1);
        }
    }

#pragma unroll
    for (int tt = 0; tt < 2; ++tt) {
        int c = (t0 + tt) * 16 + mr;
        float bv = brel[c];
#pragma unroll
        for (int sub = 0; sub < 2; ++sub)
#pragma unroll
            for (int j = 0; j < 4; ++j) {
                int r = i0 + sub * 16 + kc * 4 + j;
                if (r < n)
                    h1bf[(size_t)r * 128 + c] = f2bf(LEAKY(acc[sub][tt][j] + bv));
            }
    }
}

// ---------------------------------------------------------------------------
// Fused conv2 + gate + pool (32-row tile): paired-edge 16B gather,
// f32 LDS agg/h2, split-on-the-fly GEMMs, run-compressed pooling
// ---------------------------------------------------------------------------
__global__ __launch_bounds__(256) void conv2_gate_kernel(
    const ushort* __restrict__ h1bf, const float* __restrict__ x,
    const int* __restrict__ rowptr, const int* __restrict__ csrc,
    const float* __restrict__ cw,
    const ushort* __restrict__ W2f, const float* __restrict__ brel,
    const ushort* __restrict__ Wgf, const float* __restrict__ bsig,
    const float* __restrict__ btanh, const int* __restrict__ batch,
    float* __restrict__ pooled, int n)
{
    __shared__ __align__(16) float agg[32 * 132];   // 16896 B: agg2 -> h2 -> gs
    __shared__ int bS[32];
    float* gs = agg;                                 // alias (stride 128)

    int tid = threadIdx.x;
    int lane = tid & 63;
    int wv = tid >> 6;
    int mr = lane & 15;
    int kc = lane >> 4;
    int i0 = blockIdx.x * 32;

    // ---- gather: 32 lanes/node (2 edges x 16 lanes x 16B), 8 nodes, 4 iters ----
    {
        int q = tid & 31;
        int g = tid >> 5;
        int sub = q >> 4;        // 0: even edge, 1: odd edge
        int ql = q & 15;         // 16B chunk (8 dims)
#pragma unroll
        for (int it = 0; it < 4; ++it) {
            int rl = it * 8 + g;
            int node = i0 + rl;
            float a0 = 0.f, a1 = 0.f, a2 = 0.f, a3 = 0.f;
            float a4 = 0.f, a5 = 0.f, a6 = 0.f, a7 = 0.f;
            if (node < n) {
                int b = rowptr[node], e = rowptr[node + 1];
                for (int cb = b; cb < e; cb += 32) {
                    int cnt = e - cb; if (cnt > 32) cnt = 32;
                    int sIdx = 0; float sW = 0.f;
                    if (q < cnt) { sIdx = csrc[cb + q]; sW = cw[cb + q]; }
                    int pairs = (cnt + 1) >> 1;
                    int p = 0;
                    for (; p + 8 <= pairs; p += 8) {      // 16 edges, 128B/lane in flight
                        int si[8]; float wj[8]; uint4 v[8];
#pragma unroll
                        for (int u = 0; u < 8; ++u) {
                            int j = 2 * (p + u) + sub;
                            int jc = j < cnt ? j : cnt - 1;
                            si[u] = __shfl(sIdx, jc, 32);
                            float t = __shfl(sW, jc, 32);
                            wj[u] = (j < cnt) ? t : 0.f;
                        }
#pragma unroll
                        for (int u = 0; u < 8; ++u)
                            v[u] = *(const uint4*)(h1bf + (size_t)si[u] * 128 + ql * 8);
#pragma unroll
                        for (int u = 0; u < 8; ++u) {
                            a0 += wj[u] * u2f(v[u].x << 16);
                            a1 += wj[u] * u2f(v[u].x & 0xFFFF0000u);
                            a2 += wj[u] * u2f(v[u].y << 16);
                            a3 += wj[u] * u2f(v[u].y & 0xFFFF0000u);
                            a4 += wj[u] * u2f(v[u].z << 16);
                            a5 += wj[u] * u2f(v[u].z & 0xFFFF0000u);
                            a6 += wj[u] * u2f(v[u].w << 16);
                            a7 += wj[u] * u2f(v[u].w & 0xFFFF0000u);
                        }
                    }
                    for (; p < pairs; ++p) {
                        int j = 2 * p + sub;
                        int jc = j < cnt ? j : cnt - 1;
                        int s0 = __shfl(sIdx, jc, 32);
                        float t = __shfl(sW, jc, 32);
                        float w0 = (j < cnt) ? t : 0.f;
                        uint4 v0 = *(const uint4*)(h1bf + (size_t)s0 * 128 + ql * 8);
                        a0 += w0 * u2f(v0.x << 16);
                        a1 += w0 * u2f(v0.x & 0xFFFF0000u);
                        a2 += w0 * u2f(v0.y << 16);
                        a3 += w0 * u2f(v0.y & 0xFFFF0000u);
                        a4 += w0 * u2f(v0.z << 16);
                        a5 += w0 * u2f(v0.z & 0xFFFF0000u);
                        a6 += w0 * u2f(v0.w << 16);
                        a7 += w0 * u2f(v0.w & 0xFFFF0000u);
                    }
                }
            }
            // merge even/odd partial sums
            a0 += __shfl_xor(a0, 16, 32);
            a1 += __shfl_xor(a1, 16, 32);
            a2 += __shfl_xor(a2, 16, 32);
            a3 += __shfl_xor(a3, 16, 32);
            a4 += __shfl_xor(a4, 16, 32);
            a5 += __shfl_xor(a5, 16, 32);
            a6 += __shfl_xor(a6, 16, 32);
            a7 += __shfl_xor(a7, 16, 32);
            if (sub == 0)
                *(float4*)&agg[rl * 132 + ql * 8]     = make_float4(a0, a1, a2, a3);
            else
                *(float4*)&agg[rl * 132 + ql * 8 + 4] = make_float4(a4, a5, a6, a7);
        }
    }
    if (tid < 32) {
        int r = i0 + tid;
        bS[tid] = (r < n) ? batch[r] : -1;
    }
    __syncthreads();

    int t0 = wv * 2;

    // ---- GEMM1: h2 = leaky([agg2|h1] @ W2 + brel) ----
    f32x4 acc[2][2] = {};
    {
        const ushort* Wp = W2f + kc * 1024 + t0 * 128 + mr * 8;
#pragma unroll
        for (int kk = 0; kk < 4; ++kk) {           // A = LDS agg f32 (K 0..127)
            short8 bH0 = *(const short8*)(Wp + kk * 8192);
            short8 bH1 = *(const short8*)(Wp + kk * 8192 + 128);
            short8 bL0 = *(const short8*)(Wp + kk * 8192 + 4096);
            short8 bL1 = *(const short8*)(Wp + kk * 8192 + 4096 + 128);
#pragma unroll
            for (int sub = 0; sub < 2; ++sub) {
                short8 aH, aL;
                split8(&agg[(sub * 16 + mr) * 132 + kk * 32 + kc * 8], aH, aL);
                MFMA(acc[sub][0], aH, bH0); MFMA(acc[sub][0], aH, bL0); MFMA(acc[sub][0], aL, bH0);
                MFMA(acc[sub][1], aH, bH1); MFMA(acc[sub][1], aH, bL1); MFMA(acc[sub][1], aL, bH1);
            }
        }
#pragma unroll
        for (int kk = 4; kk < 8; ++kk) {           // A = h1bf global (K 128..255)
            short8 bH0 = *(const short8*)(Wp + kk * 8192);
            short8 bH1 = *(const short8*)(Wp + kk * 8192 + 128);
            short8 bL0 = *(const short8*)(Wp + kk * 8192 + 4096);
            short8 bL1 = *(const short8*)(Wp + kk * 8192 + 4096 + 128);
#pragma unroll
            for (int sub = 0; sub < 2; ++sub) {
                int row = i0 + sub * 16 + mr; if (row > n - 1) row = n - 1;
                short8 aH = *(const short8*)(h1bf + (size_t)row * 128 + (kk - 4) * 32 + kc * 8);
                MFMA(acc[sub][0], aH, bH0); MFMA(acc[sub][0], aH, bL0);
                MFMA(acc[sub][1], aH, bH1); MFMA(acc[sub][1], aH, bL1);
            }
        }
    }
    __syncthreads();   // all agg reads complete -> safe to overwrite with h2

#pragma unroll
    for (int tt = 0; tt < 2; ++tt) {
        int c = (t0 + tt) * 16 + mr;
        float bv = brel[c];
#pragma unroll
        for (int sub = 0; sub < 2; ++sub)
#pragma unroll
            for (int j = 0; j < 4; ++j) {
                int rl = sub * 16 + kc * 4 + j;
                agg[rl * 132 + c] = LEAKY(acc[sub][tt][j] + bv);
            }
    }
    __syncthreads();

    // ---- GEMM2: gate over [h2|x] ----
    f32x4 as[2][2] = {}, at_[2][2] = {};
    {
        const ushort* Wp = Wgf + kc * 1024 + t0 * 128 + mr * 8;
#pragma unroll
        for (int kk = 0; kk < 4; ++kk) {           // A = LDS h2 f32 (K 0..127)
            short8 sH0 = *(const short8*)(Wp + kk * 16384);
            short8 sH1 = *(const short8*)(Wp + kk * 16384 + 128);
            short8 sL0 = *(const short8*)(Wp + kk * 16384 + 4096);
            short8 sL1 = *(const short8*)(Wp + kk * 16384 + 4096 + 128);
            short8 tH0 = *(const short8*)(Wp + kk * 16384 + 8192);
            short8 tH1 = *(const short8*)(Wp + kk * 16384 + 8192 + 128);
            short8 tL0 = *(const short8*)(Wp + kk * 16384 + 12288);
            short8 tL1 = *(const short8*)(Wp + kk * 16384 + 12288 + 128);
#pragma unroll
            for (int sub = 0; sub < 2; ++sub) {
                short8 aH, aL;
                split8(&agg[(sub * 16 + mr) * 132 + kk * 32 + kc * 8], aH, aL);
                MFMA(as[sub][0], aH, sH0); MFMA(as[sub][0], aH, sL0); MFMA(as[sub][0], aL, sH0);
                MFMA(as[sub][1], aH, sH1); MFMA(as[sub][1], aH, sL1); MFMA(as[sub][1], aL, sH1);
                MFMA(at_[sub][0], aH, tH0); MFMA(at_[sub][0], aH, tL0); MFMA(at_[sub][0], aL, tH0);
                MFMA(at_[sub][1], aH, tH1); MFMA(at_[sub][1], aH, tL1); MFMA(at_[sub][1], aL, tH1);
            }
        }
#pragma unroll
        for (int kk = 4; kk < 6; ++kk) {           // A = x (K 128..191), exact split
            short8 sH0 = *(const short8*)(Wp + kk * 16384);
            short8 sH1 = *(const short8*)(Wp + kk * 16384 + 128);
            short8 sL0 = *(const short8*)(Wp + kk * 16384 + 4096);
            short8 sL1 = *(const short8*)(Wp + kk * 16384 + 4096 + 128);
            short8 tH0 = *(const short8*)(Wp + kk * 16384 + 8192);
            short8 tH1 = *(const short8*)(Wp + kk * 16384 + 8192 + 128);
            short8 tL0 = *(const short8*)(Wp + kk * 16384 + 12288);
            short8 tL1 = *(const short8*)(Wp + kk * 16384 + 12288 + 128);
#pragma unroll
            for (int sub = 0; sub < 2; ++sub) {
                int row = i0 + sub * 16 + mr; if (row > n - 1) row = n - 1;
                short8 aH, aL;
                split8(x + (size_t)row * 64 + (kk - 4) * 32 + kc * 8, aH, aL);
                MFMA(as[sub][0], aH, sH0); MFMA(as[sub][0], aH, sL0); MFMA(as[sub][0], aL, sH0);
                MFMA(as[sub][1], aH, sH1); MFMA(as[sub][1], aH, sL1); MFMA(as[sub][1], aL, sH1);
                MFMA(at_[sub][0], aH, tH0); MFMA(at_[sub][0], aH, tL0); MFMA(at_[sub][0], aL, tH0);
                MFMA(at_[sub][1], aH, tH1); MFMA(at_[sub][1], aH, tL1); MFMA(at_[sub][1], aL, tH1);
            }
        }
    }
    __syncthreads();   // h2 LDS reads complete -> safe to alias gs

    // ---- gate epilogue ----
#pragma unroll
    for (int tt = 0; tt < 2; ++tt) {
        int c = (t0 + tt) * 16 + mr;
        float bsv = bsig[c], btv = btanh[c];
#pragma unroll
        for (int sub = 0; sub < 2; ++sub)
#pragma unroll
            for (int j = 0; j < 4; ++j) {
                int rl = sub * 16 + kc * 4 + j;
                float s = as[sub][tt][j] + bsv;
                s = fminf(fmaxf(s, -30.f), 30.f);
                float ta = at_[sub][tt][j] + btv;
                ta = fminf(fmaxf(ta, -15.f), 15.f);
                float e2 = __expf(2.f * ta);
                float th = (e2 - 1.f) / (e2 + 1.f);
                gs[rl * 128 + c] = th / (1.f + __expf(s));
            }
    }
    __syncthreads();

    // ---- run-compressed pooling ----
    int j = tid & 127;
    int m0 = (tid >> 7) * 16;
    float acc2 = 0.f;
    int cur = -1;
    for (int m = m0; m < m0 + 16; ++m) {
        int b = bS[m];
        if (b < 0) break;
        if (b != cur) {
            if (cur >= 0) atomicAdd(&pooled[(size_t)cur * 128 + j], acc2);
            cur = b;
            acc2 = 0.f;
        }
        acc2 += gs[m * 128 + j];
    }
    if (cur >= 0) atomicAdd(&pooled[(size_t)cur * 128 + j], acc2);
}

// ---------------------------------------------------------------------------
// Final per-graph MLP
// ---------------------------------------------------------------------------
__global__ __launch_bounds__(256) void mlp_kernel(
    const float* __restrict__ pooled,
    const float* __restrict__ Wf1, const float* __restrict__ bf1,
    const float* __restrict__ Wf2, const float* __restrict__ bf2,
    const float* __restrict__ Wout, const float* __restrict__ bout,
    float* __restrict__ out)
{
    __shared__ float p[128];
    __shared__ float f1[128];
    __shared__ float f2[258];
    __shared__ float red[4];

    int g = blockIdx.x;
    int tid = threadIdx.x;

    if (tid < 128) p[tid] = pooled[(size_t)g * 128 + tid];
    __syncthreads();

    if (tid < 128) {
        float a = bf1[tid];
        for (int k = 0; k < 128; ++k) a += p[k] * Wf1[k * 128 + tid];
        f1[tid] = LEAKY(a);
    }
    __syncthreads();

    for (int j = tid; j < 258; j += 256) {
        float a = bf2[j];
        for (int k = 0; k < 128; ++k) a += f1[k] * Wf2[k * 258 + j];
        f2[j] = LEAKY(a);
    }
    __syncthreads();

    float a = 0.f;
    for (int j = tid; j < 258; j += 256) a += f2[j] * Wout[j];
#pragma unroll
    for (int off = 32; off > 0; off >>= 1) a += __shfl_down(a, off, 64);
    if ((tid & 63) == 0) red[tid >> 6] = a;
    __syncthreads();
    if (tid == 0) {
        float v = red[0] + red[1] + red[2] + red[3] + bout[0];
        out[g] = 1.f / (1.f + expf(-v));
    }
}

// ---------------------------------------------------------------------------
extern "C" void kernel_launch(void* const* d_in, const int* in_sizes, int n_in,
                              void* d_out, int out_size, void* d_ws, size_t ws_size,
                              hipStream_t stream)
{
    const float* x     = (const float*)d_in[0];
    const int*   ei    = (const int*)d_in[1];
    const int*   batch = (const int*)d_in[2];
    const float* ea    = (const float*)d_in[3];
    const float* Wrel1 = (const float*)d_in[4];
    const float* brel1 = (const float*)d_in[5];
    const float* Wroot1= (const float*)d_in[6];
    const float* Wrel2 = (const float*)d_in[7];
    const float* brel2 = (const float*)d_in[8];
    const float* Wroot2= (const float*)d_in[9];
    const float* Wsig  = (const float*)d_in[10];
    const float* bsig  = (const float*)d_in[11];
    const float* Wtanh = (const float*)d_in[12];
    const float* btanh = (const float*)d_in[13];
    const float* Wf1   = (const float*)d_in[14];
    const float* bf1   = (const float*)d_in[15];
    const float* Wf2   = (const float*)d_in[16];
    const float* bf2   = (const float*)d_in[17];
    const float* Wout  = (const float*)d_in[18];
    const float* bout  = (const float*)d_in[19];

    int N = in_sizes[2];
    int E = in_sizes[3];

    char* base = (char*)d_ws;
    size_t off = 0;
    auto alloc = [&](size_t bytes) {
        char* p = base + off;
        off += (bytes + 255) & ~(size_t)255;
        return p;
    };
    ushort*   h1bf  = (ushort*)alloc((size_t)N * 128 * 2);
    ushort*   xbf   = (ushort*)alloc((size_t)N * 64 * 2);
    int*      rowptr= (int*)alloc((size_t)(N + 1) * 4);
    int*      cursor= (int*)alloc((size_t)N * 4);
    int*      bsum  = (int*)alloc(512 * 4);
    int*      csrc  = (int*)alloc((size_t)E * 4);
    float*    cwgt  = (float*)alloc((size_t)E * 4);
    ushort*   W1f   = (ushort*)alloc(32768 * 2);
    ushort*   W2f   = (ushort*)alloc(65536 * 2);
    ushort*   Wgf   = (ushort*)alloc(98304 * 2);
    float*    pooled= (float*)alloc(256 * 128 * 4);

    int eblk = (E + 255) / 256;
    int nblk1 = (N + 1023) / 1024;
    int cblk = (N + 31) / 32;

    hipMemsetAsync(cursor, 0, (size_t)N * sizeof(int), stream);
    hipMemsetAsync(pooled, 0, (size_t)256 * 128 * sizeof(float), stream);

    prep_weights_kernel<<<768, 256, 0, stream>>>(Wrel1, Wroot1, Wrel2, Wroot2,
                                                 Wsig, Wtanh, W1f, W2f, Wgf);
    xbf_kernel<<<(N * 16 + 255) / 256, 256, 0, stream>>>(x, xbf, N * 16);

    // ---- CSR build ----
    hist_kernel<<<eblk, 256, 0, stream>>>(ei, cursor, E);
    scan1_kernel<<<nblk1, 256, 0, stream>>>(cursor, rowptr, bsum, N);
    scan2_kernel<<<1, 512, 0, stream>>>(bsum, nblk1);
    scan3_kernel<<<(N + 255) / 256, 256, 0, stream>>>(rowptr, bsum, N, E);
    hipMemcpyAsync(cursor, rowptr, (size_t)N * sizeof(int),
                   hipMemcpyDeviceToDevice, stream);
    fill_kernel<<<eblk, 256, 0, stream>>>(ei, ea, cursor, csrc, cwgt, E);

    // ---- fused conv1 (gather + GEMM) ----
    conv1_fused_kernel<<<cblk, 256, 0, stream>>>(x, xbf, rowptr, csrc, cwgt,
                                                 W1f, brel1, h1bf, N);

    // ---- fused conv2 + gate + pool (gather + 2 GEMMs) ----
    conv2_gate_kernel<<<cblk, 256, 0, stream>>>(h1bf, x, rowptr, csrc, cwgt,
                                                W2f, brel2, Wgf, bsig, btanh,
                                                batch, pooled, N);

    // ---- final MLP ----
    mlp_kernel<<<256, 256, 0, stream>>>(pooled, Wf1, bf1, Wf2, bf2, Wout, bout,
                                        (float*)d_out);
}

// Round 9
// 444.595 us; speedup vs baseline: 1.1006x; 1.1006x over previous
//
#include <hip/hip_runtime.h>
#include <cstdint>

#define RELU_COEF 0.05f
#define LEAKY(v) ((v) > 0.f ? (v) : RELU_COEF * (v))

typedef __attribute__((ext_vector_type(8))) short short8;
typedef __attribute__((ext_vector_type(4))) float f32x4;

#define MFMA(acc, a, b) \
    acc = __builtin_amdgcn_mfma_f32_16x16x32_bf16(a, b, acc, 0, 0, 0)

__device__ inline ushort f2bf(float f) {
    union { float f; uint32_t u; } v; v.f = f;
    return (ushort)((v.u + 0x7FFFu + ((v.u >> 16) & 1u)) >> 16);
}
__device__ inline float bf2f(ushort h) {
    union { uint32_t u; float f; } v; v.u = ((uint32_t)h) << 16;
    return v.f;
}
__device__ inline void split8(const float* p, short8& h8, short8& l8) {
    float4 a = *(const float4*)p;
    float4 b = *(const float4*)(p + 4);
    float v[8] = {a.x, a.y, a.z, a.w, b.x, b.y, b.z, b.w};
    short8 hh, ll;
#pragma unroll
    for (int i = 0; i < 8; ++i) {
        ushort hi = f2bf(v[i]);
        hh[i] = (short)hi;
        ll[i] = (short)f2bf(v[i] - bf2f(hi));
    }
    h8 = hh; l8 = ll;
}

// ---------------------------------------------------------------------------
// CSR build
// ---------------------------------------------------------------------------
__global__ __launch_bounds__(256) void hist_kernel(
    const int* __restrict__ ei, int* __restrict__ deg, int E)
{
    int e = blockIdx.x * 256 + threadIdx.x;
    if (e >= E) return;
    atomicAdd(&deg[ei[(size_t)E + e]], 1);
}

__global__ __launch_bounds__(256) void scan1_kernel(
    const int* __restrict__ in, int* __restrict__ out, int* __restrict__ bsum, int N)
{
    __shared__ int ts[256];
    int tid = threadIdx.x;
    int base = blockIdx.x * 1024 + tid * 4;
    int v[4];
    int s = 0;
#pragma unroll
    for (int j = 0; j < 4; ++j) {
        int idx = base + j;
        v[j] = (idx < N) ? in[idx] : 0;
        s += v[j];
    }
    ts[tid] = s;
    __syncthreads();
    for (int off = 1; off < 256; off <<= 1) {
        int t = (tid >= off) ? ts[tid - off] : 0;
        __syncthreads();
        ts[tid] += t;
        __syncthreads();
    }
    int excl = ts[tid] - s;
    if (tid == 255) bsum[blockIdx.x] = ts[255];
    int run = excl;
#pragma unroll
    for (int j = 0; j < 4; ++j) {
        int idx = base + j;
        if (idx < N) out[idx] = run;
        run += v[j];
    }
}

__global__ __launch_bounds__(512) void scan2_kernel(int* bsum, int nb)
{
    __shared__ int ts[512];
    int tid = threadIdx.x;
    int v = (tid < nb) ? bsum[tid] : 0;
    ts[tid] = v;
    __syncthreads();
    for (int off = 1; off < 512; off <<= 1) {
        int t = (tid >= off) ? ts[tid - off] : 0;
        __syncthreads();
        ts[tid] += t;
        __syncthreads();
    }
    if (tid < nb) bsum[tid] = ts[tid] - v;
}

__global__ __launch_bounds__(256) void scan3_kernel(
    int* __restrict__ rowptr, const int* __restrict__ bsum, int N, int E)
{
    int idx = blockIdx.x * 256 + threadIdx.x;
    if (idx < N) rowptr[idx] += bsum[idx >> 10];
    if (idx == 0) rowptr[N] = E;
}

__global__ __launch_bounds__(256) void fill_kernel(
    const int* __restrict__ ei, const float* __restrict__ ea,
    int* __restrict__ cursor, int* __restrict__ csrc, float* __restrict__ cw, int E)
{
    int e = blockIdx.x * 256 + threadIdx.x;
    if (e >= E) return;
    int t = ei[(size_t)E + e];
    int pos = atomicAdd(&cursor[t], 1);
    csrc[pos] = ei[e];
    cw[pos] = ea[e];
}

// ---------------------------------------------------------------------------
// x -> bf16 copy (gather payload for conv1)
// ---------------------------------------------------------------------------
__global__ __launch_bounds__(256) void xbf_kernel(
    const float* __restrict__ x, ushort* __restrict__ xbf, int total4)
{
    int i = blockIdx.x * 256 + threadIdx.x;
    if (i >= total4) return;
    float4 v = *(const float4*)(x + (size_t)i * 4);
    ushort4 h;
    h.x = f2bf(v.x); h.y = f2bf(v.y); h.z = f2bf(v.z); h.w = f2bf(v.w);
    *(ushort4*)(xbf + (size_t)i * 4) = h;
}

// ---------------------------------------------------------------------------
// Weight prep -> fragment-major split-bf16 layouts (coalesced B loads):
// W1f[kk:4][hl:2][kc:4][n:128][e:8]   (K=128: agg1|x)
// W2f[kk:8][hl:2][kc:4][n:128][e:8]   (K=256: agg2|h1)
// Wgf[kk:6][p:4 (sH,sL,tH,tL)][kc:4][n:128][e:8]  (K=192: h2|x)
// ---------------------------------------------------------------------------
__global__ __launch_bounds__(256) void prep_weights_kernel(
    const float* __restrict__ Wrel1, const float* __restrict__ Wroot1,
    const float* __restrict__ Wrel2, const float* __restrict__ Wroot2,
    const float* __restrict__ Wsig, const float* __restrict__ Wtanh,
    ushort* __restrict__ W1f, ushort* __restrict__ W2f, ushort* __restrict__ Wgf)
{
    int gid = blockIdx.x * 256 + threadIdx.x;
    if (gid < 32768) {
        int e = gid & 7, nn = (gid >> 3) & 127, kc = (gid >> 10) & 3;
        int hl = (gid >> 12) & 1, kk = gid >> 13;
        int k = kk * 32 + kc * 8 + e;
        float v = (k < 64) ? Wrel1[(size_t)k * 128 + nn]
                           : Wroot1[(size_t)(k - 64) * 128 + nn];
        ushort hi = f2bf(v);
        W1f[gid] = hl ? f2bf(v - bf2f(hi)) : hi;
        return;
    }
    int g2 = gid - 32768;
    if (g2 < 65536) {
        int e = g2 & 7, nn = (g2 >> 3) & 127, kc = (g2 >> 10) & 3;
        int hl = (g2 >> 12) & 1, kk = g2 >> 13;
        int k = kk * 32 + kc * 8 + e;
        float v = (k < 128) ? Wrel2[(size_t)k * 128 + nn]
                            : Wroot2[(size_t)(k - 128) * 128 + nn];
        ushort hi = f2bf(v);
        W2f[g2] = hl ? f2bf(v - bf2f(hi)) : hi;
        return;
    }
    int g3 = g2 - 65536;
    if (g3 < 98304) {
        int e = g3 & 7, nn = (g3 >> 3) & 127, kc = (g3 >> 10) & 3;
        int p = (g3 >> 12) & 3, kk = g3 >> 14;
        int k = kk * 32 + kc * 8 + e;
        float v = (p < 2) ? Wsig[(size_t)k * 128 + nn]
                          : Wtanh[(size_t)k * 128 + nn];
        ushort hi = f2bf(v);
        Wgf[g3] = (p & 1) ? f2bf(v - bf2f(hi)) : hi;
    }
}

// ---------------------------------------------------------------------------
// Standalone gather (conv1): agg1bf[node] = bf16( sum w * xbf[src] )
// 16 lanes/node, shfl-broadcast indices, 8-deep independent loads. No LDS.
// ---------------------------------------------------------------------------
__global__ __launch_bounds__(256) void gather64_kernel(
    const ushort* __restrict__ xbf, const int* __restrict__ rowptr,
    const int* __restrict__ csrc, const float* __restrict__ cw,
    ushort* __restrict__ agg1bf, int N)
{
    int q = threadIdx.x & 15;
    int node = blockIdx.x * 16 + (threadIdx.x >> 4);
    if (node >= N) return;
    float ax = 0.f, ay = 0.f, az = 0.f, aw = 0.f;
    int b = rowptr[node], e = rowptr[node + 1];
    for (int cb = b; cb < e; cb += 16) {
        int cnt = e - cb; if (cnt > 16) cnt = 16;
        int sIdx = 0; float sW = 0.f;
        if (q < cnt) { sIdx = csrc[cb + q]; sW = cw[cb + q]; }
        int j = 0;
        for (; j + 8 <= cnt; j += 8) {
            int si[8]; float wi[8]; ushort4 fv[8];
#pragma unroll
            for (int u = 0; u < 8; ++u) {
                si[u] = __shfl(sIdx, j + u, 16);
                wi[u] = __shfl(sW, j + u, 16);
            }
#pragma unroll
            for (int u = 0; u < 8; ++u)
                fv[u] = *(const ushort4*)(xbf + (size_t)si[u] * 64 + q * 4);
#pragma unroll
            for (int u = 0; u < 8; ++u) {
                ax += wi[u] * bf2f(fv[u].x);
                ay += wi[u] * bf2f(fv[u].y);
                az += wi[u] * bf2f(fv[u].z);
                aw += wi[u] * bf2f(fv[u].w);
            }
        }
        for (; j < cnt; ++j) {
            int s0 = __shfl(sIdx, j, 16); float w0 = __shfl(sW, j, 16);
            ushort4 f0 = *(const ushort4*)(xbf + (size_t)s0 * 64 + q * 4);
            ax += w0 * bf2f(f0.x); ay += w0 * bf2f(f0.y);
            az += w0 * bf2f(f0.z); aw += w0 * bf2f(f0.w);
        }
    }
    ushort4 h;
    h.x = f2bf(ax); h.y = f2bf(ay); h.z = f2bf(az); h.w = f2bf(aw);
    *(ushort4*)(agg1bf + (size_t)node * 64 + q * 4) = h;
}

// ---------------------------------------------------------------------------
// Standalone gather (conv2): agg2bf[node] = bf16( sum w * h1bf[src] )
// 32 lanes/node. No LDS, no barriers -> minimal VGPR, max occupancy.
// ---------------------------------------------------------------------------
__global__ __launch_bounds__(256) void gather128_kernel(
    const ushort* __restrict__ h1bf, const int* __restrict__ rowptr,
    const int* __restrict__ csrc, const float* __restrict__ cw,
    ushort* __restrict__ agg2bf, int N)
{
    int q = threadIdx.x & 31;
    int node = blockIdx.x * 8 + (threadIdx.x >> 5);
    if (node >= N) return;
    float ax = 0.f, ay = 0.f, az = 0.f, aw = 0.f;
    int b = rowptr[node], e = rowptr[node + 1];
    for (int cb = b; cb < e; cb += 32) {
        int cnt = e - cb; if (cnt > 32) cnt = 32;
        int sIdx = 0; float sW = 0.f;
        if (q < cnt) { sIdx = csrc[cb + q]; sW = cw[cb + q]; }
        int j = 0;
        for (; j + 8 <= cnt; j += 8) {
            int si[8]; float wi[8]; ushort4 fv[8];
#pragma unroll
            for (int u = 0; u < 8; ++u) {
                si[u] = __shfl(sIdx, j + u, 32);
                wi[u] = __shfl(sW, j + u, 32);
            }
#pragma unroll
            for (int u = 0; u < 8; ++u)
                fv[u] = *(const ushort4*)(h1bf + (size_t)si[u] * 128 + q * 4);
#pragma unroll
            for (int u = 0; u < 8; ++u) {
                ax += wi[u] * bf2f(fv[u].x);
                ay += wi[u] * bf2f(fv[u].y);
                az += wi[u] * bf2f(fv[u].z);
                aw += wi[u] * bf2f(fv[u].w);
            }
        }
        for (; j < cnt; ++j) {
            int s0 = __shfl(sIdx, j, 32); float w0 = __shfl(sW, j, 32);
            ushort4 f0 = *(const ushort4*)(h1bf + (size_t)s0 * 128 + q * 4);
            ax += w0 * bf2f(f0.x); ay += w0 * bf2f(f0.y);
            az += w0 * bf2f(f0.z); aw += w0 * bf2f(f0.w);
        }
    }
    ushort4 h;
    h.x = f2bf(ax); h.y = f2bf(ay); h.z = f2bf(az); h.w = f2bf(aw);
    *(ushort4*)(agg2bf + (size_t)node * 128 + q * 4) = h;
}

// ---------------------------------------------------------------------------
// conv1 GEMM (streaming, no LDS/barriers): h1bf = bf16(leaky([agg1|x]@W1+b))
// 32-row tile, 4 waves; agg half bf16-direct (2 MFMA), x half split (3 MFMA).
// ---------------------------------------------------------------------------
__global__ __launch_bounds__(256) void conv1_kernel(
    const float* __restrict__ x, const ushort* __restrict__ agg1bf,
    const ushort* __restrict__ W1f, const float* __restrict__ brel,
    ushort* __restrict__ h1bf, int n)
{
    int tid = threadIdx.x;
    int lane = tid & 63;
    int wv = tid >> 6;
    int mr = lane & 15;
    int kc = lane >> 4;
    int i0 = blockIdx.x * 32;
    int t0 = wv * 2;
    const ushort* Wp = W1f + kc * 1024 + t0 * 128 + mr * 8;
    f32x4 acc[2][2] = {};

#pragma unroll
    for (int kk = 0; kk < 2; ++kk) {      // A = agg1bf (K 0..63), bf16 direct
        short8 bH0 = *(const short8*)(Wp + kk * 8192);
        short8 bH1 = *(const short8*)(Wp + kk * 8192 + 128);
        short8 bL0 = *(const short8*)(Wp + kk * 8192 + 4096);
        short8 bL1 = *(const short8*)(Wp + kk * 8192 + 4096 + 128);
#pragma unroll
        for (int sub = 0; sub < 2; ++sub) {
            int row = i0 + sub * 16 + mr; if (row > n - 1) row = n - 1;
            short8 aH = *(const short8*)(agg1bf + (size_t)row * 64 + kk * 32 + kc * 8);
            MFMA(acc[sub][0], aH, bH0); MFMA(acc[sub][0], aH, bL0);
            MFMA(acc[sub][1], aH, bH1); MFMA(acc[sub][1], aH, bL1);
        }
    }
#pragma unroll
    for (int kk = 2; kk < 4; ++kk) {      // A = x (K 64..127), exact split
        short8 bH0 = *(const short8*)(Wp + kk * 8192);
        short8 bH1 = *(const short8*)(Wp + kk * 8192 + 128);
        short8 bL0 = *(const short8*)(Wp + kk * 8192 + 4096);
        short8 bL1 = *(const short8*)(Wp + kk * 8192 + 4096 + 128);
#pragma unroll
        for (int sub = 0; sub < 2; ++sub) {
            int row = i0 + sub * 16 + mr; if (row > n - 1) row = n - 1;
            short8 aH, aL;
            split8(x + (size_t)row * 64 + (kk - 2) * 32 + kc * 8, aH, aL);
            MFMA(acc[sub][0], aH, bH0); MFMA(acc[sub][0], aH, bL0); MFMA(acc[sub][0], aL, bH0);
            MFMA(acc[sub][1], aH, bH1); MFMA(acc[sub][1], aH, bL1); MFMA(acc[sub][1], aL, bH1);
        }
    }

#pragma unroll
    for (int tt = 0; tt < 2; ++tt) {
        int c = (t0 + tt) * 16 + mr;
        float bv = brel[c];
#pragma unroll
        for (int sub = 0; sub < 2; ++sub)
#pragma unroll
            for (int j = 0; j < 4; ++j) {
                int r = i0 + sub * 16 + kc * 4 + j;
                if (r < n)
                    h1bf[(size_t)r * 128 + c] = f2bf(LEAKY(acc[sub][tt][j] + bv));
            }
    }
}

// ---------------------------------------------------------------------------
// conv2 + gate + pool GEMM (streaming): reads agg2bf/h1bf/x, h2 in LDS,
// gate epilogue, run-compressed pooling.
// ---------------------------------------------------------------------------
__global__ __launch_bounds__(256) void conv2_gate_kernel(
    const ushort* __restrict__ agg2bf, const ushort* __restrict__ h1bf,
    const float* __restrict__ x,
    const ushort* __restrict__ W2f, const float* __restrict__ brel,
    const ushort* __restrict__ Wgf, const float* __restrict__ bsig,
    const float* __restrict__ btanh, const int* __restrict__ batch,
    float* __restrict__ pooled, int n)
{
    __shared__ __align__(16) float h2s[32 * 132];   // 16896 B: h2 -> gs
    __shared__ int bS[32];
    float* gs = h2s;                                 // alias (stride 128)

    int tid = threadIdx.x;
    int lane = tid & 63;
    int wv = tid >> 6;
    int mr = lane & 15;
    int kc = lane >> 4;
    int i0 = blockIdx.x * 32;
    int t0 = wv * 2;

    if (tid < 32) {
        int r = i0 + tid;
        bS[tid] = (r < n) ? batch[r] : -1;
    }

    // ---- GEMM1: h2 = leaky([agg2|h1] @ W2 + brel) ----
    f32x4 acc[2][2] = {};
    {
        const ushort* Wp = W2f + kc * 1024 + t0 * 128 + mr * 8;
#pragma unroll
        for (int kk = 0; kk < 4; ++kk) {           // A = agg2bf (K 0..127)
            short8 bH0 = *(const short8*)(Wp + kk * 8192);
            short8 bH1 = *(const short8*)(Wp + kk * 8192 + 128);
            short8 bL0 = *(const short8*)(Wp + kk * 8192 + 4096);
            short8 bL1 = *(const short8*)(Wp + kk * 8192 + 4096 + 128);
#pragma unroll
            for (int sub = 0; sub < 2; ++sub) {
                int row = i0 + sub * 16 + mr; if (row > n - 1) row = n - 1;
                short8 aH = *(const short8*)(agg2bf + (size_t)row * 128 + kk * 32 + kc * 8);
                MFMA(acc[sub][0], aH, bH0); MFMA(acc[sub][0], aH, bL0);
                MFMA(acc[sub][1], aH, bH1); MFMA(acc[sub][1], aH, bL1);
            }
        }
#pragma unroll
        for (int kk = 4; kk < 8; ++kk) {           // A = h1bf (K 128..255)
            short8 bH0 = *(const short8*)(Wp + kk * 8192);
            short8 bH1 = *(const short8*)(Wp + kk * 8192 + 128);
            short8 bL0 = *(const short8*)(Wp + kk * 8192 + 4096);
            short8 bL1 = *(const short8*)(Wp + kk * 8192 + 4096 + 128);
#pragma unroll
            for (int sub = 0; sub < 2; ++sub) {
                int row = i0 + sub * 16 + mr; if (row > n - 1) row = n - 1;
                short8 aH = *(const short8*)(h1bf + (size_t)row * 128 + (kk - 4) * 32 + kc * 8);
                MFMA(acc[sub][0], aH, bH0); MFMA(acc[sub][0], aH, bL0);
                MFMA(acc[sub][1], aH, bH1); MFMA(acc[sub][1], aH, bL1);
            }
        }
    }

#pragma unroll
    for (int tt = 0; tt < 2; ++tt) {
        int c = (t0 + tt) * 16 + mr;
        float bv = brel[c];
#pragma unroll
        for (int sub = 0; sub < 2; ++sub)
#pragma unroll
            for (int j = 0; j < 4; ++j) {
                int rl = sub * 16 + kc * 4 + j;
                h2s[rl * 132 + c] = LEAKY(acc[sub][tt][j] + bv);
            }
    }
    __syncthreads();

    // ---- GEMM2: gate over [h2|x] ----
    f32x4 as[2][2] = {}, at_[2][2] = {};
    {
        const ushort* Wp = Wgf + kc * 1024 + t0 * 128 + mr * 8;
#pragma unroll
        for (int kk = 0; kk < 4; ++kk) {           // A = LDS h2 f32 (K 0..127)
            short8 sH0 = *(const short8*)(Wp + kk * 16384);
            short8 sH1 = *(const short8*)(Wp + kk * 16384 + 128);
            short8 sL0 = *(const short8*)(Wp + kk * 16384 + 4096);
            short8 sL1 = *(const short8*)(Wp + kk * 16384 + 4096 + 128);
            short8 tH0 = *(const short8*)(Wp + kk * 16384 + 8192);
            short8 tH1 = *(const short8*)(Wp + kk * 16384 + 8192 + 128);
            short8 tL0 = *(const short8*)(Wp + kk * 16384 + 12288);
            short8 tL1 = *(const short8*)(Wp + kk * 16384 + 12288 + 128);
#pragma unroll
            for (int sub = 0; sub < 2; ++sub) {
                short8 aH, aL;
                split8(&h2s[(sub * 16 + mr) * 132 + kk * 32 + kc * 8], aH, aL);
                MFMA(as[sub][0], aH, sH0); MFMA(as[sub][0], aH, sL0); MFMA(as[sub][0], aL, sH0);
                MFMA(as[sub][1], aH, sH1); MFMA(as[sub][1], aH, sL1); MFMA(as[sub][1], aL, sH1);
                MFMA(at_[sub][0], aH, tH0); MFMA(at_[sub][0], aH, tL0); MFMA(at_[sub][0], aL, tH0);
                MFMA(at_[sub][1], aH, tH1); MFMA(at_[sub][1], aH, tL1); MFMA(at_[sub][1], aL, tH1);
            }
        }
#pragma unroll
        for (int kk = 4; kk < 6; ++kk) {           // A = x (K 128..191), exact split
            short8 sH0 = *(const short8*)(Wp + kk * 16384);
            short8 sH1 = *(const short8*)(Wp + kk * 16384 + 128);
            short8 sL0 = *(const short8*)(Wp + kk * 16384 + 4096);
            short8 sL1 = *(const short8*)(Wp + kk * 16384 + 4096 + 128);
            short8 tH0 = *(const short8*)(Wp + kk * 16384 + 8192);
            short8 tH1 = *(const short8*)(Wp + kk * 16384 + 8192 + 128);
            short8 tL0 = *(const short8*)(Wp + kk * 16384 + 12288);
            short8 tL1 = *(const short8*)(Wp + kk * 16384 + 12288 + 128);
#pragma unroll
            for (int sub = 0; sub < 2; ++sub) {
                int row = i0 + sub * 16 + mr; if (row > n - 1) row = n - 1;
                short8 aH, aL;
                split8(x + (size_t)row * 64 + (kk - 4) * 32 + kc * 8, aH, aL);
                MFMA(as[sub][0], aH, sH0); MFMA(as[sub][0], aH, sL0); MFMA(as[sub][0], aL, sH0);
                MFMA(as[sub][1], aH, sH1); MFMA(as[sub][1], aH, sL1); MFMA(as[sub][1], aL, sH1);
                MFMA(at_[sub][0], aH, tH0); MFMA(at_[sub][0], aH, tL0); MFMA(at_[sub][0], aL, tH0);
                MFMA(at_[sub][1], aH, tH1); MFMA(at_[sub][1], aH, tL1); MFMA(at_[sub][1], aL, tH1);
            }
        }
    }
    __syncthreads();   // h2 LDS reads complete -> safe to alias gs

    // ---- gate epilogue ----
#pragma unroll
    for (int tt = 0; tt < 2; ++tt) {
        int c = (t0 + tt) * 16 + mr;
        float bsv = bsig[c], btv = btanh[c];
#pragma unroll
        for (int sub = 0; sub < 2; ++sub)
#pragma unroll
            for (int j = 0; j < 4; ++j) {
                int rl = sub * 16 + kc * 4 + j;
                float s = as[sub][tt][j] + bsv;
                s = fminf(fmaxf(s, -30.f), 30.f);
                float ta = at_[sub][tt][j] + btv;
                ta = fminf(fmaxf(ta, -15.f), 15.f);
                float e2 = __expf(2.f * ta);
                float th = (e2 - 1.f) / (e2 + 1.f);
                gs[rl * 128 + c] = th / (1.f + __expf(s));
            }
    }
    __syncthreads();

    // ---- run-compressed pooling ----
    int j = tid & 127;
    int m0 = (tid >> 7) * 16;
    float acc2 = 0.f;
    int cur = -1;
    for (int m = m0; m < m0 + 16; ++m) {
        int b = bS[m];
        if (b < 0) break;
        if (b != cur) {
            if (cur >= 0) atomicAdd(&pooled[(size_t)cur * 128 + j], acc2);
            cur = b;
            acc2 = 0.f;
        }
        acc2 += gs[m * 128 + j];
    }
    if (cur >= 0) atomicAdd(&pooled[(size_t)cur * 128 + j], acc2);
}

// ---------------------------------------------------------------------------
// Final per-graph MLP
// ---------------------------------------------------------------------------
__global__ __launch_bounds__(256) void mlp_kernel(
    const float* __restrict__ pooled,
    const float* __restrict__ Wf1, const float* __restrict__ bf1,
    const float* __restrict__ Wf2, const float* __restrict__ bf2,
    const float* __restrict__ Wout, const float* __restrict__ bout,
    float* __restrict__ out)
{
    __shared__ float p[128];
    __shared__ float f1[128];
    __shared__ float f2[258];
    __shared__ float red[4];

    int g = blockIdx.x;
    int tid = threadIdx.x;

    if (tid < 128) p[tid] = pooled[(size_t)g * 128 + tid];
    __syncthreads();

    if (tid < 128) {
        float a = bf1[tid];
        for (int k = 0; k < 128; ++k) a += p[k] * Wf1[k * 128 + tid];
        f1[tid] = LEAKY(a);
    }
    __syncthreads();

    for (int j = tid; j < 258; j += 256) {
        float a = bf2[j];
        for (int k = 0; k < 128; ++k) a += f1[k] * Wf2[k * 258 + j];
        f2[j] = LEAKY(a);
    }
    __syncthreads();

    float a = 0.f;
    for (int j = tid; j < 258; j += 256) a += f2[j] * Wout[j];
#pragma unroll
    for (int off = 32; off > 0; off >>= 1) a += __shfl_down(a, off, 64);
    if ((tid & 63) == 0) red[tid >> 6] = a;
    __syncthreads();
    if (tid == 0) {
        float v = red[0] + red[1] + red[2] + red[3] + bout[0];
        out[g] = 1.f / (1.f + expf(-v));
    }
}

// ---------------------------------------------------------------------------
extern "C" void kernel_launch(void* const* d_in, const int* in_sizes, int n_in,
                              void* d_out, int out_size, void* d_ws, size_t ws_size,
                              hipStream_t stream)
{
    const float* x     = (const float*)d_in[0];
    const int*   ei    = (const int*)d_in[1];
    const int*   batch = (const int*)d_in[2];
    const float* ea    = (const float*)d_in[3];
    const float* Wrel1 = (const float*)d_in[4];
    const float* brel1 = (const float*)d_in[5];
    const float* Wroot1= (const float*)d_in[6];
    const float* Wrel2 = (const float*)d_in[7];
    const float* brel2 = (const float*)d_in[8];
    const float* Wroot2= (const float*)d_in[9];
    const float* Wsig  = (const float*)d_in[10];
    const float* bsig  = (const float*)d_in[11];
    const float* Wtanh = (const float*)d_in[12];
    const float* btanh = (const float*)d_in[13];
    const float* Wf1   = (const float*)d_in[14];
    const float* bf1   = (const float*)d_in[15];
    const float* Wf2   = (const float*)d_in[16];
    const float* bf2   = (const float*)d_in[17];
    const float* Wout  = (const float*)d_in[18];
    const float* bout  = (const float*)d_in[19];

    int N = in_sizes[2];
    int E = in_sizes[3];

    char* base = (char*)d_ws;
    size_t off = 0;
    auto alloc = [&](size_t bytes) {
        char* p = base + off;
        off += (bytes + 255) & ~(size_t)255;
        return p;
    };
    ushort*   h1bf  = (ushort*)alloc((size_t)N * 128 * 2);
    ushort*   xbf   = (ushort*)alloc((size_t)N * 64 * 2);
    ushort*   agg1bf= (ushort*)alloc((size_t)N * 64 * 2);
    ushort*   agg2bf= (ushort*)alloc((size_t)N * 128 * 2);
    int*      rowptr= (int*)alloc((size_t)(N + 1) * 4);
    int*      cursor= (int*)alloc((size_t)N * 4);
    int*      bsum  = (int*)alloc(512 * 4);
    int*      csrc  = (int*)alloc((size_t)E * 4);
    float*    cwgt  = (float*)alloc((size_t)E * 4);
    ushort*   W1f   = (ushort*)alloc(32768 * 2);
    ushort*   W2f   = (ushort*)alloc(65536 * 2);
    ushort*   Wgf   = (ushort*)alloc(98304 * 2);
    float*    pooled= (float*)alloc(256 * 128 * 4);

    int eblk = (E + 255) / 256;
    int nblk1 = (N + 1023) / 1024;
    int cblk = (N + 31) / 32;

    hipMemsetAsync(cursor, 0, (size_t)N * sizeof(int), stream);
    hipMemsetAsync(pooled, 0, (size_t)256 * 128 * sizeof(float), stream);

    prep_weights_kernel<<<768, 256, 0, stream>>>(Wrel1, Wroot1, Wrel2, Wroot2,
                                                 Wsig, Wtanh, W1f, W2f, Wgf);
    xbf_kernel<<<(N * 16 + 255) / 256, 256, 0, stream>>>(x, xbf, N * 16);

    // ---- CSR build ----
    hist_kernel<<<eblk, 256, 0, stream>>>(ei, cursor, E);
    scan1_kernel<<<nblk1, 256, 0, stream>>>(cursor, rowptr, bsum, N);
    scan2_kernel<<<1, 512, 0, stream>>>(bsum, nblk1);
    scan3_kernel<<<(N + 255) / 256, 256, 0, stream>>>(rowptr, bsum, N, E);
    hipMemcpyAsync(cursor, rowptr, (size_t)N * sizeof(int),
                   hipMemcpyDeviceToDevice, stream);
    fill_kernel<<<eblk, 256, 0, stream>>>(ei, ea, cursor, csrc, cwgt, E);

    // ---- conv1: gather then GEMM ----
    gather64_kernel<<<(N + 15) / 16, 256, 0, stream>>>(xbf, rowptr, csrc, cwgt,
                                                       agg1bf, N);
    conv1_kernel<<<cblk, 256, 0, stream>>>(x, agg1bf, W1f, brel1, h1bf, N);

    // ---- conv2 + gate + pool: gather then GEMM ----
    gather128_kernel<<<(N + 7) / 8, 256, 0, stream>>>(h1bf, rowptr, csrc, cwgt,
                                                      agg2bf, N);
    conv2_gate_kernel<<<cblk, 256, 0, stream>>>(agg2bf, h1bf, x, W2f, brel2,
                                                Wgf, bsig, btanh, batch,
                                                pooled, N);

    // ---- final MLP ----
    mlp_kernel<<<256, 256, 0, stream>>>(pooled, Wf1, bf1, Wf2, bf2, Wout, bout,
                                        (float*)d_out);
}

// Round 10
// 425.056 us; speedup vs baseline: 1.1512x; 1.0460x over previous
//
#include <hip/hip_runtime.h>
#include <cstdint>

#define RELU_COEF 0.05f
#define LEAKY(v) ((v) > 0.f ? (v) : RELU_COEF * (v))

typedef __attribute__((ext_vector_type(8))) short short8;
typedef __attribute__((ext_vector_type(4))) float f32x4;

#define MFMA(acc, a, b) \
    acc = __builtin_amdgcn_mfma_f32_16x16x32_bf16(a, b, acc, 0, 0, 0)

__device__ inline ushort f2bf(float f) {
    union { float f; uint32_t u; } v; v.f = f;
    return (ushort)((v.u + 0x7FFFu + ((v.u >> 16) & 1u)) >> 16);
}
__device__ inline float bf2f(ushort h) {
    union { uint32_t u; float f; } v; v.u = ((uint32_t)h) << 16;
    return v.f;
}
__device__ inline void split8(const float* p, short8& h8, short8& l8) {
    float4 a = *(const float4*)p;
    float4 b = *(const float4*)(p + 4);
    float v[8] = {a.x, a.y, a.z, a.w, b.x, b.y, b.z, b.w};
    short8 hh, ll;
#pragma unroll
    for (int i = 0; i < 8; ++i) {
        ushort hi = f2bf(v[i]);
        hh[i] = (short)hi;
        ll[i] = (short)f2bf(v[i] - bf2f(hi));
    }
    h8 = hh; l8 = ll;
}

// ---------------------------------------------------------------------------
// CSR build
// ---------------------------------------------------------------------------
__global__ __launch_bounds__(256) void hist_kernel(
    const int* __restrict__ ei, int* __restrict__ deg, int E)
{
    int e = blockIdx.x * 256 + threadIdx.x;
    if (e >= E) return;
    atomicAdd(&deg[ei[(size_t)E + e]], 1);
}

__global__ __launch_bounds__(256) void scan1_kernel(
    const int* __restrict__ in, int* __restrict__ out, int* __restrict__ bsum, int N)
{
    __shared__ int ts[256];
    int tid = threadIdx.x;
    int base = blockIdx.x * 1024 + tid * 4;
    int v[4];
    int s = 0;
#pragma unroll
    for (int j = 0; j < 4; ++j) {
        int idx = base + j;
        v[j] = (idx < N) ? in[idx] : 0;
        s += v[j];
    }
    ts[tid] = s;
    __syncthreads();
    for (int off = 1; off < 256; off <<= 1) {
        int t = (tid >= off) ? ts[tid - off] : 0;
        __syncthreads();
        ts[tid] += t;
        __syncthreads();
    }
    int excl = ts[tid] - s;
    if (tid == 255) bsum[blockIdx.x] = ts[255];
    int run = excl;
#pragma unroll
    for (int j = 0; j < 4; ++j) {
        int idx = base + j;
        if (idx < N) out[idx] = run;
        run += v[j];
    }
}

__global__ __launch_bounds__(512) void scan2_kernel(int* bsum, int nb)
{
    __shared__ int ts[512];
    int tid = threadIdx.x;
    int v = (tid < nb) ? bsum[tid] : 0;
    ts[tid] = v;
    __syncthreads();
    for (int off = 1; off < 512; off <<= 1) {
        int t = (tid >= off) ? ts[tid - off] : 0;
        __syncthreads();
        ts[tid] += t;
        __syncthreads();
    }
    if (tid < nb) bsum[tid] = ts[tid] - v;
}

__global__ __launch_bounds__(256) void scan3_kernel(
    int* __restrict__ rowptr, const int* __restrict__ bsum, int N, int E)
{
    int idx = blockIdx.x * 256 + threadIdx.x;
    if (idx < N) rowptr[idx] += bsum[idx >> 10];
    if (idx == 0) rowptr[N] = E;
}

// fill: single 8B packed store per edge (src idx, fp32 weight)
__global__ __launch_bounds__(256) void fill_kernel(
    const int* __restrict__ ei, const float* __restrict__ ea,
    int* __restrict__ cursor, int2* __restrict__ csw, int E)
{
    int e = blockIdx.x * 256 + threadIdx.x;
    if (e >= E) return;
    int t = ei[(size_t)E + e];
    int pos = atomicAdd(&cursor[t], 1);
    csw[pos] = make_int2(ei[e], __float_as_int(ea[e]));
}

// ---------------------------------------------------------------------------
// x -> bf16 copy (gather payload for conv1)
// ---------------------------------------------------------------------------
__global__ __launch_bounds__(256) void xbf_kernel(
    const float* __restrict__ x, ushort* __restrict__ xbf, int total4)
{
    int i = blockIdx.x * 256 + threadIdx.x;
    if (i >= total4) return;
    float4 v = *(const float4*)(x + (size_t)i * 4);
    ushort4 h;
    h.x = f2bf(v.x); h.y = f2bf(v.y); h.z = f2bf(v.z); h.w = f2bf(v.w);
    *(ushort4*)(xbf + (size_t)i * 4) = h;
}

// ---------------------------------------------------------------------------
// Weight prep -> fragment-major split-bf16 layouts (coalesced B loads):
// W1f[kk:4][hl:2][kc:4][n:128][e:8]   (K=128: agg1|x)
// W2f[kk:8][hl:2][kc:4][n:128][e:8]   (K=256: agg2|h1)
// Wgf[kk:6][p:4 (sH,sL,tH,tL)][kc:4][n:128][e:8]  (K=192: h2|x)
// ---------------------------------------------------------------------------
__global__ __launch_bounds__(256) void prep_weights_kernel(
    const float* __restrict__ Wrel1, const float* __restrict__ Wroot1,
    const float* __restrict__ Wrel2, const float* __restrict__ Wroot2,
    const float* __restrict__ Wsig, const float* __restrict__ Wtanh,
    ushort* __restrict__ W1f, ushort* __restrict__ W2f, ushort* __restrict__ Wgf)
{
    int gid = blockIdx.x * 256 + threadIdx.x;
    if (gid < 32768) {
        int e = gid & 7, nn = (gid >> 3) & 127, kc = (gid >> 10) & 3;
        int hl = (gid >> 12) & 1, kk = gid >> 13;
        int k = kk * 32 + kc * 8 + e;
        float v = (k < 64) ? Wrel1[(size_t)k * 128 + nn]
                           : Wroot1[(size_t)(k - 64) * 128 + nn];
        ushort hi = f2bf(v);
        W1f[gid] = hl ? f2bf(v - bf2f(hi)) : hi;
        return;
    }
    int g2 = gid - 32768;
    if (g2 < 65536) {
        int e = g2 & 7, nn = (g2 >> 3) & 127, kc = (g2 >> 10) & 3;
        int hl = (g2 >> 12) & 1, kk = g2 >> 13;
        int k = kk * 32 + kc * 8 + e;
        float v = (k < 128) ? Wrel2[(size_t)k * 128 + nn]
                            : Wroot2[(size_t)(k - 128) * 128 + nn];
        ushort hi = f2bf(v);
        W2f[g2] = hl ? f2bf(v - bf2f(hi)) : hi;
        return;
    }
    int g3 = g2 - 65536;
    if (g3 < 98304) {
        int e = g3 & 7, nn = (g3 >> 3) & 127, kc = (g3 >> 10) & 3;
        int p = (g3 >> 12) & 3, kk = g3 >> 14;
        int k = kk * 32 + kc * 8 + e;
        float v = (p < 2) ? Wsig[(size_t)k * 128 + nn]
                          : Wtanh[(size_t)k * 128 + nn];
        ushort hi = f2bf(v);
        Wgf[g3] = (p & 1) ? f2bf(v - bf2f(hi)) : hi;
    }
}

// ---------------------------------------------------------------------------
// Fused conv1 (32-row tile, f32 LDS agg): h1bf = bf16(leaky([agg1|x]@W1 + b))
// ---------------------------------------------------------------------------
__global__ __launch_bounds__(256) void conv1_fused_kernel(
    const float* __restrict__ x, const ushort* __restrict__ xbf,
    const int* __restrict__ rowptr, const int2* __restrict__ csw,
    const ushort* __restrict__ W1f, const float* __restrict__ brel,
    ushort* __restrict__ h1bf, int n)
{
    __shared__ __align__(16) float agg[32 * 68];   // 8704 B

    int tid = threadIdx.x;
    int lane = tid & 63;
    int wv = tid >> 6;
    int mr = lane & 15;
    int kc = lane >> 4;          // 0..3
    int i0 = blockIdx.x * 32;

    // ---- gather phase: 16 lanes/node, 16 groups, 2 iters ----
    {
        int q = tid & 15;
        int g = tid >> 4;
#pragma unroll
        for (int it = 0; it < 2; ++it) {
            int rl = it * 16 + g;
            int node = i0 + rl;
            float ax = 0.f, ay = 0.f, az = 0.f, aw = 0.f;
            if (node < n) {
                int b = rowptr[node], e = rowptr[node + 1];
                for (int cb = b; cb < e; cb += 16) {
                    int cnt = e - cb; if (cnt > 16) cnt = 16;
                    int sIdx = 0; float sW = 0.f;
                    if (q < cnt) {
                        int2 p = csw[cb + q];
                        sIdx = p.x; sW = __int_as_float(p.y);
                    }
                    int j = 0;
                    for (; j + 8 <= cnt; j += 8) {
                        int si[8]; float wi[8]; ushort4 fv[8];
#pragma unroll
                        for (int u = 0; u < 8; ++u) {
                            si[u] = __shfl(sIdx, j + u, 16);
                            wi[u] = __shfl(sW, j + u, 16);
                        }
#pragma unroll
                        for (int u = 0; u < 8; ++u)
                            fv[u] = *(const ushort4*)(xbf + (size_t)si[u] * 64 + q * 4);
#pragma unroll
                        for (int u = 0; u < 8; ++u) {
                            ax += wi[u] * bf2f(fv[u].x);
                            ay += wi[u] * bf2f(fv[u].y);
                            az += wi[u] * bf2f(fv[u].z);
                            aw += wi[u] * bf2f(fv[u].w);
                        }
                    }
                    for (; j < cnt; ++j) {
                        int s0 = __shfl(sIdx, j, 16); float w0 = __shfl(sW, j, 16);
                        ushort4 f0 = *(const ushort4*)(xbf + (size_t)s0 * 64 + q * 4);
                        ax += w0 * bf2f(f0.x); ay += w0 * bf2f(f0.y);
                        az += w0 * bf2f(f0.z); aw += w0 * bf2f(f0.w);
                    }
                }
            }
            *(float4*)&agg[rl * 68 + q * 4] = make_float4(ax, ay, az, aw);
        }
    }
    __syncthreads();

    // ---- GEMM ----
    int t0 = wv * 2;
    const ushort* Wp = W1f + kc * 1024 + t0 * 128 + mr * 8;
    f32x4 acc[2][2] = {};

#pragma unroll
    for (int kk = 0; kk < 2; ++kk) {      // A from LDS agg (K 0..63), split on the fly
        short8 bH0 = *(const short8*)(Wp + kk * 8192);
        short8 bH1 = *(const short8*)(Wp + kk * 8192 + 128);
        short8 bL0 = *(const short8*)(Wp + kk * 8192 + 4096);
        short8 bL1 = *(const short8*)(Wp + kk * 8192 + 4096 + 128);
#pragma unroll
        for (int sub = 0; sub < 2; ++sub) {
            short8 aH, aL;
            split8(&agg[(sub * 16 + mr) * 68 + kk * 32 + kc * 8], aH, aL);
            MFMA(acc[sub][0], aH, bH0); MFMA(acc[sub][0], aH, bL0); MFMA(acc[sub][0], aL, bH0);
            MFMA(acc[sub][1], aH, bH1); MFMA(acc[sub][1], aH, bL1); MFMA(acc[sub][1], aL, bH1);
        }
    }
#pragma unroll
    for (int kk = 2; kk < 4; ++kk) {      // A from x (K 64..127), exact split
        short8 bH0 = *(const short8*)(Wp + kk * 8192);
        short8 bH1 = *(const short8*)(Wp + kk * 8192 + 128);
        short8 bL0 = *(const short8*)(Wp + kk * 8192 + 4096);
        short8 bL1 = *(const short8*)(Wp + kk * 8192 + 4096 + 128);
#pragma unroll
        for (int sub = 0; sub < 2; ++sub) {
            int row = i0 + sub * 16 + mr; if (row > n - 1) row = n - 1;
            short8 aH, aL;
            split8(x + (size_t)row * 64 + (kk - 2) * 32 + kc * 8, aH, aL);
            MFMA(acc[sub][0], aH, bH0); MFMA(acc[sub][0], aH, bL0); MFMA(acc[sub][0], aL, bH0);
            MFMA(acc[sub][1], aH, bH1); MFMA(acc[sub][1], aH, bL1); MFMA(acc[sub][1], aL, bH1);
        }
    }

#pragma unroll
    for (int tt = 0; tt < 2; ++tt) {
        int c = (t0 + tt) * 16 + mr;
        float bv = brel[c];
#pragma unroll
        for (int sub = 0; sub < 2; ++sub)
#pragma unroll
            for (int j = 0; j < 4; ++j) {
                int r = i0 + sub * 16 + kc * 4 + j;
                if (r < n)
                    h1bf[(size_t)r * 128 + c] = f2bf(LEAKY(acc[sub][tt][j] + bv));
            }
    }
}

// ---------------------------------------------------------------------------
// Fused conv2 + gate + pool (32-row tile, f32 LDS agg/h2, split on the fly)
// ---------------------------------------------------------------------------
__global__ __launch_bounds__(256) void conv2_gate_kernel(
    const ushort* __restrict__ h1bf, const float* __restrict__ x,
    const int* __restrict__ rowptr, const int2* __restrict__ csw,
    const ushort* __restrict__ W2f, const float* __restrict__ brel,
    const ushort* __restrict__ Wgf, const float* __restrict__ bsig,
    const float* __restrict__ btanh, const int* __restrict__ batch,
    float* __restrict__ pooled, int n)
{
    __shared__ __align__(16) float agg[32 * 132];   // 16896 B: agg2 -> h2 -> gs
    __shared__ int bS[32];
    float* gs = agg;                                 // alias (stride 128)

    int tid = threadIdx.x;
    int lane = tid & 63;
    int wv = tid >> 6;
    int mr = lane & 15;
    int kc = lane >> 4;
    int i0 = blockIdx.x * 32;

    // ---- gather phase: 32 lanes/node, 8 groups, 4 iters ----
    {
        int q = tid & 31;
        int g = tid >> 5;
#pragma unroll
        for (int it = 0; it < 4; ++it) {
            int rl = it * 8 + g;
            int node = i0 + rl;
            float ax = 0.f, ay = 0.f, az = 0.f, aw = 0.f;
            if (node < n) {
                int b = rowptr[node], e = rowptr[node + 1];
                for (int cb = b; cb < e; cb += 32) {
                    int cnt = e - cb; if (cnt > 32) cnt = 32;
                    int sIdx = 0; float sW = 0.f;
                    if (q < cnt) {
                        int2 p = csw[cb + q];
                        sIdx = p.x; sW = __int_as_float(p.y);
                    }
                    int j = 0;
                    for (; j + 8 <= cnt; j += 8) {
                        int si[8]; float wi[8]; ushort4 fv[8];
#pragma unroll
                        for (int u = 0; u < 8; ++u) {
                            si[u] = __shfl(sIdx, j + u, 32);
                            wi[u] = __shfl(sW, j + u, 32);
                        }
#pragma unroll
                        for (int u = 0; u < 8; ++u)
                            fv[u] = *(const ushort4*)(h1bf + (size_t)si[u] * 128 + q * 4);
#pragma unroll
                        for (int u = 0; u < 8; ++u) {
                            ax += wi[u] * bf2f(fv[u].x);
                            ay += wi[u] * bf2f(fv[u].y);
                            az += wi[u] * bf2f(fv[u].z);
                            aw += wi[u] * bf2f(fv[u].w);
                        }
                    }
                    for (; j < cnt; ++j) {
                        int s0 = __shfl(sIdx, j, 32); float w0 = __shfl(sW, j, 32);
                        ushort4 f0 = *(const ushort4*)(h1bf + (size_t)s0 * 128 + q * 4);
                        ax += w0 * bf2f(f0.x); ay += w0 * bf2f(f0.y);
                        az += w0 * bf2f(f0.z); aw += w0 * bf2f(f0.w);
                    }
                }
            }
            *(float4*)&agg[rl * 132 + q * 4] = make_float4(ax, ay, az, aw);
        }
    }
    if (tid < 32) {
        int r = i0 + tid;
        bS[tid] = (r < n) ? batch[r] : -1;
    }
    __syncthreads();

    int t0 = wv * 2;

    // ---- GEMM1: h2 = leaky([agg2|h1] @ W2 + brel) ----
    f32x4 acc[2][2] = {};
    {
        const ushort* Wp = W2f + kc * 1024 + t0 * 128 + mr * 8;
#pragma unroll
        for (int kk = 0; kk < 4; ++kk) {           // A = LDS agg f32 (K 0..127)
            short8 bH0 = *(const short8*)(Wp + kk * 8192);
            short8 bH1 = *(const short8*)(Wp + kk * 8192 + 128);
            short8 bL0 = *(const short8*)(Wp + kk * 8192 + 4096);
            short8 bL1 = *(const short8*)(Wp + kk * 8192 + 4096 + 128);
#pragma unroll
            for (int sub = 0; sub < 2; ++sub) {
                short8 aH, aL;
                split8(&agg[(sub * 16 + mr) * 132 + kk * 32 + kc * 8], aH, aL);
                MFMA(acc[sub][0], aH, bH0); MFMA(acc[sub][0], aH, bL0); MFMA(acc[sub][0], aL, bH0);
                MFMA(acc[sub][1], aH, bH1); MFMA(acc[sub][1], aH, bL1); MFMA(acc[sub][1], aL, bH1);
            }
        }
#pragma unroll
        for (int kk = 4; kk < 8; ++kk) {           // A = h1bf global (K 128..255)
            short8 bH0 = *(const short8*)(Wp + kk * 8192);
            short8 bH1 = *(const short8*)(Wp + kk * 8192 + 128);
            short8 bL0 = *(const short8*)(Wp + kk * 8192 + 4096);
            short8 bL1 = *(const short8*)(Wp + kk * 8192 + 4096 + 128);
#pragma unroll
            for (int sub = 0; sub < 2; ++sub) {
                int row = i0 + sub * 16 + mr; if (row > n - 1) row = n - 1;
                short8 aH = *(const short8*)(h1bf + (size_t)row * 128 + (kk - 4) * 32 + kc * 8);
                MFMA(acc[sub][0], aH, bH0); MFMA(acc[sub][0], aH, bL0);
                MFMA(acc[sub][1], aH, bH1); MFMA(acc[sub][1], aH, bL1);
            }
        }
    }
    __syncthreads();   // all agg reads complete -> safe to overwrite with h2

#pragma unroll
    for (int tt = 0; tt < 2; ++tt) {
        int c = (t0 + tt) * 16 + mr;
        float bv = brel[c];
#pragma unroll
        for (int sub = 0; sub < 2; ++sub)
#pragma unroll
            for (int j = 0; j < 4; ++j) {
                int rl = sub * 16 + kc * 4 + j;
                agg[rl * 132 + c] = LEAKY(acc[sub][tt][j] + bv);
            }
    }
    __syncthreads();

    // ---- GEMM2: gate over [h2|x] ----
    f32x4 as[2][2] = {}, at_[2][2] = {};
    {
        const ushort* Wp = Wgf + kc * 1024 + t0 * 128 + mr * 8;
#pragma unroll
        for (int kk = 0; kk < 4; ++kk) {           // A = LDS h2 f32 (K 0..127)
            short8 sH0 = *(const short8*)(Wp + kk * 16384);
            short8 sH1 = *(const short8*)(Wp + kk * 16384 + 128);
            short8 sL0 = *(const short8*)(Wp + kk * 16384 + 4096);
            short8 sL1 = *(const short8*)(Wp + kk * 16384 + 4096 + 128);
            short8 tH0 = *(const short8*)(Wp + kk * 16384 + 8192);
            short8 tH1 = *(const short8*)(Wp + kk * 16384 + 8192 + 128);
            short8 tL0 = *(const short8*)(Wp + kk * 16384 + 12288);
            short8 tL1 = *(const short8*)(Wp + kk * 16384 + 12288 + 128);
#pragma unroll
            for (int sub = 0; sub < 2; ++sub) {
                short8 aH, aL;
                split8(&agg[(sub * 16 + mr) * 132 + kk * 32 + kc * 8], aH, aL);
                MFMA(as[sub][0], aH, sH0); MFMA(as[sub][0], aH, sL0); MFMA(as[sub][0], aL, sH0);
                MFMA(as[sub][1], aH, sH1); MFMA(as[sub][1], aH, sL1); MFMA(as[sub][1], aL, sH1);
                MFMA(at_[sub][0], aH, tH0); MFMA(at_[sub][0], aH, tL0); MFMA(at_[sub][0], aL, tH0);
                MFMA(at_[sub][1], aH, tH1); MFMA(at_[sub][1], aH, tL1); MFMA(at_[sub][1], aL, tH1);
            }
        }
#pragma unroll
        for (int kk = 4; kk < 6; ++kk) {           // A = x (K 128..191), exact split
            short8 sH0 = *(const short8*)(Wp + kk * 16384);
            short8 sH1 = *(const short8*)(Wp + kk * 16384 + 128);
            short8 sL0 = *(const short8*)(Wp + kk * 16384 + 4096);
            short8 sL1 = *(const short8*)(Wp + kk * 16384 + 4096 + 128);
            short8 tH0 = *(const short8*)(Wp + kk * 16384 + 8192);
            short8 tH1 = *(const short8*)(Wp + kk * 16384 + 8192 + 128);
            short8 tL0 = *(const short8*)(Wp + kk * 16384 + 12288);
            short8 tL1 = *(const short8*)(Wp + kk * 16384 + 12288 + 128);
#pragma unroll
            for (int sub = 0; sub < 2; ++sub) {
                int row = i0 + sub * 16 + mr; if (row > n - 1) row = n - 1;
                short8 aH, aL;
                split8(x + (size_t)row * 64 + (kk - 4) * 32 + kc * 8, aH, aL);
                MFMA(as[sub][0], aH, sH0); MFMA(as[sub][0], aH, sL0); MFMA(as[sub][0], aL, sH0);
                MFMA(as[sub][1], aH, sH1); MFMA(as[sub][1], aH, sL1); MFMA(as[sub][1], aL, sH1);
                MFMA(at_[sub][0], aH, tH0); MFMA(at_[sub][0], aH, tL0); MFMA(at_[sub][0], aL, tH0);
                MFMA(at_[sub][1], aH, tH1); MFMA(at_[sub][1], aH, tL1); MFMA(at_[sub][1], aL, tH1);
            }
        }
    }
    __syncthreads();   // h2 LDS reads complete -> safe to alias gs

    // ---- gate epilogue ----
#pragma unroll
    for (int tt = 0; tt < 2; ++tt) {
        int c = (t0 + tt) * 16 + mr;
        float bsv = bsig[c], btv = btanh[c];
#pragma unroll
        for (int sub = 0; sub < 2; ++sub)
#pragma unroll
            for (int j = 0; j < 4; ++j) {
                int rl = sub * 16 + kc * 4 + j;
                float s = as[sub][tt][j] + bsv;
                s = fminf(fmaxf(s, -30.f), 30.f);
                float ta = at_[sub][tt][j] + btv;
                ta = fminf(fmaxf(ta, -15.f), 15.f);
                float e2 = __expf(2.f * ta);
                float th = (e2 - 1.f) / (e2 + 1.f);
                gs[rl * 128 + c] = th / (1.f + __expf(s));
            }
    }
    __syncthreads();

    // ---- run-compressed pooling ----
    int j = tid & 127;
    int m0 = (tid >> 7) * 16;
    float acc2 = 0.f;
    int cur = -1;
    for (int m = m0; m < m0 + 16; ++m) {
        int b = bS[m];
        if (b < 0) break;
        if (b != cur) {
            if (cur >= 0) atomicAdd(&pooled[(size_t)cur * 128 + j], acc2);
            cur = b;
            acc2 = 0.f;
        }
        acc2 += gs[m * 128 + j];
    }
    if (cur >= 0) atomicAdd(&pooled[(size_t)cur * 128 + j], acc2);
}

// ---------------------------------------------------------------------------
// Final per-graph MLP
// ---------------------------------------------------------------------------
__global__ __launch_bounds__(256) void mlp_kernel(
    const float* __restrict__ pooled,
    const float* __restrict__ Wf1, const float* __restrict__ bf1,
    const float* __restrict__ Wf2, const float* __restrict__ bf2,
    const float* __restrict__ Wout, const float* __restrict__ bout,
    float* __restrict__ out)
{
    __shared__ float p[128];
    __shared__ float f1[128];
    __shared__ float f2[258];
    __shared__ float red[4];

    int g = blockIdx.x;
    int tid = threadIdx.x;

    if (tid < 128) p[tid] = pooled[(size_t)g * 128 + tid];
    __syncthreads();

    if (tid < 128) {
        float a = bf1[tid];
        for (int k = 0; k < 128; ++k) a += p[k] * Wf1[k * 128 + tid];
        f1[tid] = LEAKY(a);
    }
    __syncthreads();

    for (int j = tid; j < 258; j += 256) {
        float a = bf2[j];
        for (int k = 0; k < 128; ++k) a += f1[k] * Wf2[k * 258 + j];
        f2[j] = LEAKY(a);
    }
    __syncthreads();

    float a = 0.f;
    for (int j = tid; j < 258; j += 256) a += f2[j] * Wout[j];
#pragma unroll
    for (int off = 32; off > 0; off >>= 1) a += __shfl_down(a, off, 64);
    if ((tid & 63) == 0) red[tid >> 6] = a;
    __syncthreads();
    if (tid == 0) {
        float v = red[0] + red[1] + red[2] + red[3] + bout[0];
        out[g] = 1.f / (1.f + expf(-v));
    }
}

// ---------------------------------------------------------------------------
extern "C" void kernel_launch(void* const* d_in, const int* in_sizes, int n_in,
                              void* d_out, int out_size, void* d_ws, size_t ws_size,
                              hipStream_t stream)
{
    const float* x     = (const float*)d_in[0];
    const int*   ei    = (const int*)d_in[1];
    const int*   batch = (const int*)d_in[2];
    const float* ea    = (const float*)d_in[3];
    const float* Wrel1 = (const float*)d_in[4];
    const float* brel1 = (const float*)d_in[5];
    const float* Wroot1= (const float*)d_in[6];
    const float* Wrel2 = (const float*)d_in[7];
    const float* brel2 = (const float*)d_in[8];
    const float* Wroot2= (const float*)d_in[9];
    const float* Wsig  = (const float*)d_in[10];
    const float* bsig  = (const float*)d_in[11];
    const float* Wtanh = (const float*)d_in[12];
    const float* btanh = (const float*)d_in[13];
    const float* Wf1   = (const float*)d_in[14];
    const float* bf1   = (const float*)d_in[15];
    const float* Wf2   = (const float*)d_in[16];
    const float* bf2   = (const float*)d_in[17];
    const float* Wout  = (const float*)d_in[18];
    const float* bout  = (const float*)d_in[19];

    int N = in_sizes[2];
    int E = in_sizes[3];

    char* base = (char*)d_ws;
    size_t off = 0;
    auto alloc = [&](size_t bytes) {
        char* p = base + off;
        off += (bytes + 255) & ~(size_t)255;
        return p;
    };
    ushort*   h1bf  = (ushort*)alloc((size_t)N * 128 * 2);
    ushort*   xbf   = (ushort*)alloc((size_t)N * 64 * 2);
    int*      rowptr= (int*)alloc((size_t)(N + 1) * 4);
    int*      cursor= (int*)alloc((size_t)N * 4);
    int*      bsum  = (int*)alloc(512 * 4);
    int2*     csw   = (int2*)alloc((size_t)E * 8);
    ushort*   W1f   = (ushort*)alloc(32768 * 2);
    ushort*   W2f   = (ushort*)alloc(65536 * 2);
    ushort*   Wgf   = (ushort*)alloc(98304 * 2);
    float*    pooled= (float*)alloc(256 * 128 * 4);

    int eblk = (E + 255) / 256;
    int nblk1 = (N + 1023) / 1024;
    int cblk = (N + 31) / 32;

    hipMemsetAsync(cursor, 0, (size_t)N * sizeof(int), stream);
    hipMemsetAsync(pooled, 0, (size_t)256 * 128 * sizeof(float), stream);

    prep_weights_kernel<<<768, 256, 0, stream>>>(Wrel1, Wroot1, Wrel2, Wroot2,
                                                 Wsig, Wtanh, W1f, W2f, Wgf);
    xbf_kernel<<<(N * 16 + 255) / 256, 256, 0, stream>>>(x, xbf, N * 16);

    // ---- CSR build ----
    hist_kernel<<<eblk, 256, 0, stream>>>(ei, cursor, E);
    scan1_kernel<<<nblk1, 256, 0, stream>>>(cursor, rowptr, bsum, N);
    scan2_kernel<<<1, 512, 0, stream>>>(bsum, nblk1);
    scan3_kernel<<<(N + 255) / 256, 256, 0, stream>>>(rowptr, bsum, N, E);
    hipMemcpyAsync(cursor, rowptr, (size_t)N * sizeof(int),
                   hipMemcpyDeviceToDevice, stream);
    fill_kernel<<<eblk, 256, 0, stream>>>(ei, ea, cursor, csw, E);

    // ---- fused conv1 (gather + GEMM) ----
    conv1_fused_kernel<<<cblk, 256, 0, stream>>>(x, xbf, rowptr, csw,
                                                 W1f, brel1, h1bf, N);

    // ---- fused conv2 + gate + pool (gather + 2 GEMMs) ----
    conv2_gate_kernel<<<cblk, 256, 0, stream>>>(h1bf, x, rowptr, csw,
                                                W2f, brel2, Wgf, bsig, btanh,
                                                batch, pooled, N);

    // ---- final MLP ----
    mlp_kernel<<<256, 256, 0, stream>>>(pooled, Wf1, bf1, Wf2, bf2, Wout, bout,
                                        (float*)d_out);
}